// Round 2
// baseline (894.522 us; speedup 1.0000x reference)
//
#include <hip/hip_runtime.h>

// QuantMatMul: fake-quant(A) @ fake-quant(B), computed exactly via i8 MFMA.
// A: [4,4096,4096] fp32 -> folded to M=16384 rows. B: [4096,4096] fp32 (K x N).
// C = s_a*s_b * ( A'B' - zb*rowsumA[m] - za*colsumB[n] + K*za*zb ),  A',B' in i8.
//
// Round 4: 256x128 tile, BK=64, 512 threads / 8 waves of 128x32 (acc[4]),
// LDS double-buffer 2x24KiB -> 2 blocks/CU (16 waves/CU). Per tile: STAGE next
// slot (3 per-lane pre-swizzled global_load_lds) -> 10 ds_read_b128 -> 8 MFMA
// -> one __syncthreads (vmcnt drain covered by a full tile of compute + the
// co-resident block). Global layouts are PLAIN (no swizzle); the conflict-free
// LDS arrangement (4 rows per 256B pseudo-row, 3-bit XOR) is produced by
// per-lane global source addressing into a lane-linear LDS dest (m173 pattern).
// ds_read addresses are tile-invariant: precomputed once, slot-1 via imm offset.

#define K_DIM 4096
#define N_COLS 4096
#define M_ROWS 16384

typedef __attribute__((ext_vector_type(4))) int int4v;
typedef __attribute__((ext_vector_type(16))) int int16v;

// ---- workspace layout ----
static const size_t OFF_AQ = 0;                                  // 64 MiB  i8 [16384][4096] (plain)
static const size_t OFF_BT = (size_t)64 << 20;                   // 16 MiB  i8 [4096][4096] (B^T, plain)
static const size_t OFF_RS = OFF_BT + ((size_t)16 << 20);        // 64 KiB  int rowsumA
static const size_t OFF_CS = OFF_RS + (size_t)M_ROWS * 4;        // 16 KiB  int colsumB
static const size_t OFF_MM = OFF_CS + (size_t)N_COLS * 4;        // 64 B    minmax enc

// sortable encoding for float atomic min/max
__device__ __forceinline__ unsigned enc_f(float f) {
  unsigned u = __float_as_uint(f);
  return (u & 0x80000000u) ? ~u : (u | 0x80000000u);
}
__device__ __forceinline__ float dec_f(unsigned e) {
  unsigned u = (e & 0x80000000u) ? (e & 0x7fffffffu) : ~e;
  return __uint_as_float(u);
}

// reciprocal-multiply quantize: matches ref's clip(rint(x/s)+zp,0,255), -128 shift
__device__ __forceinline__ int quantize1(float x, float r, float zp) {
  return (int)(fminf(fmaxf(rintf(x * r) + zp, 0.0f), 255.0f)) - 128;
}

__device__ __forceinline__ void gload16(const void* g, void* l) {
  __builtin_amdgcn_global_load_lds(
      (const __attribute__((address_space(1))) unsigned int*)g,
      (__attribute__((address_space(3))) unsigned int*)l, 16, 0, 0);
}

// per-block inline param computation (deterministic; identical fp ops everywhere)
__device__ __forceinline__ void qparams_a(const unsigned* mm, float& ra, float& zpa) {
  const float amin = dec_f(mm[0]), amax = dec_f(mm[1]);
  const float sa = fmaxf((amax - amin) / 255.0f, 1e-8f);
  zpa = rintf(-amin / sa);
  ra = 1.0f / sa;
}
__device__ __forceinline__ void qparams_b(const unsigned* mm, float& rb, float& zpb) {
  const float bmin = dec_f(mm[2]), bmax = dec_f(mm[3]);
  const float sb = fmaxf((bmax - bmin) / 255.0f, 1e-8f);
  zpb = rintf(-bmin / sb);
  rb = 1.0f / sb;
}

__global__ void init_mm_k(unsigned* mm) {
  if (threadIdx.x == 0) {
    mm[0] = 0xFFFFFFFFu; mm[1] = 0u;   // A min/max (encoded)
    mm[2] = 0xFFFFFFFFu; mm[3] = 0u;   // B min/max
  }
}

// fused minmax over A (blocks 0..4095) and B (blocks 4096..5119)
__global__ __launch_bounds__(256) void minmax_k(const float4* __restrict__ A,
                                                const float4* __restrict__ B,
                                                unsigned* __restrict__ mm) {
  const bool isB = blockIdx.x >= 4096;
  const float4* __restrict__ x = isB ? B : A;
  const long n4 = isB ? (long)K_DIM * N_COLS / 4 : (long)M_ROWS * K_DIM / 4;
  const int nblk = isB ? 1024 : 4096;
  const int bid = isB ? (int)blockIdx.x - 4096 : (int)blockIdx.x;
  unsigned* m = mm + (isB ? 2 : 0);

  float lo = 3.402823466e38f, hi = -3.402823466e38f;
  long i = (long)bid * blockDim.x + threadIdx.x;
  const long stride = (long)nblk * blockDim.x;
  for (; i < n4; i += stride) {
    float4 v = x[i];
    lo = fminf(lo, fminf(fminf(v.x, v.y), fminf(v.z, v.w)));
    hi = fmaxf(hi, fmaxf(fmaxf(v.x, v.y), fmaxf(v.z, v.w)));
  }
  for (int off = 32; off; off >>= 1) {
    lo = fminf(lo, __shfl_down(lo, off));
    hi = fmaxf(hi, __shfl_down(hi, off));
  }
  __shared__ float slo[4], shi[4];
  const int t = threadIdx.x;
  if ((t & 63) == 0) { slo[t >> 6] = lo; shi[t >> 6] = hi; }
  __syncthreads();
  if (t == 0) {
    for (int w = 1; w < 4; w++) { lo = fminf(lo, slo[w]); hi = fmaxf(hi, shi[w]); }
    atomicMin(&m[0], enc_f(lo));
    atomicMax(&m[1], enc_f(hi));
  }
}

// one block per row: quantize (plain coalesced layout) + rowsum
__global__ __launch_bounds__(256) void quantA_k(const float* __restrict__ A,
                                                signed char* __restrict__ Aq,
                                                int* __restrict__ rowsum,
                                                const unsigned* __restrict__ mm) {
  float ra, zpa;
  qparams_a(mm, ra, zpa);
  const int row = blockIdx.x, t = threadIdx.x;
  const float4* src = (const float4*)(A + (size_t)row * K_DIM);
  unsigned* dst = (unsigned*)(Aq + (size_t)row * K_DIM);
  int sum = 0;
#pragma unroll
  for (int j = 0; j < 4; j++) {
    const int d = j * 256 + t;           // dword index in row (0..1023)
    float4 v = src[d];
    int q0 = quantize1(v.x, ra, zpa);
    int q1 = quantize1(v.y, ra, zpa);
    int q2 = quantize1(v.z, ra, zpa);
    int q3 = quantize1(v.w, ra, zpa);
    sum += q0 + q1 + q2 + q3;
    dst[d] = ((unsigned)q0 & 255u) | (((unsigned)q1 & 255u) << 8) |
             (((unsigned)q2 & 255u) << 16) | (((unsigned)q3 & 255u) << 24);
  }
  for (int off = 32; off; off >>= 1) sum += __shfl_down(sum, off);
  __shared__ int sw[4];
  if ((t & 63) == 0) sw[t >> 6] = sum;
  __syncthreads();
  if (t == 0) rowsum[row] = sw[0] + sw[1] + sw[2] + sw[3];
}

// quantize B, transpose to Bt[N][K] via 64x64 LDS tile (plain output layout)
__global__ __launch_bounds__(256) void quantB_k(const float* __restrict__ B,
                                                signed char* __restrict__ Bt,
                                                const unsigned* __restrict__ mm) {
  float rb, zpb;
  qparams_b(mm, rb, zpb);
  __shared__ unsigned char s[64][72];
  const int n0 = blockIdx.x * 64, k0 = blockIdx.y * 64;
  const int t = threadIdx.x;
  const int kr = t >> 2, tl = t & 3;
  const float* rowp = B + (size_t)(k0 + kr) * N_COLS + n0;
#pragma unroll
  for (int j = 0; j < 4; j++) {
    const int fi = tl + j * 4;
    float4 v = *(const float4*)(rowp + fi * 4);
    int q0 = quantize1(v.x, rb, zpb);
    int q1 = quantize1(v.y, rb, zpb);
    int q2 = quantize1(v.z, rb, zpb);
    int q3 = quantize1(v.w, rb, zpb);
    *(unsigned*)&s[kr][fi * 4] = ((unsigned)q0 & 255u) | (((unsigned)q1 & 255u) << 8) |
                                 (((unsigned)q2 & 255u) << 16) | (((unsigned)q3 & 255u) << 24);
  }
  __syncthreads();
  const int nr = t >> 2;                 // output row within tile (n)
  const int kb = tl * 16;                // 16-byte K block within 64B chunk
  unsigned w[4];
#pragma unroll
  for (int jj = 0; jj < 4; jj++) {
    unsigned b0 = s[kb + jj * 4 + 0][nr];
    unsigned b1 = s[kb + jj * 4 + 1][nr];
    unsigned b2 = s[kb + jj * 4 + 2][nr];
    unsigned b3 = s[kb + jj * 4 + 3][nr];
    w[jj] = b0 | (b1 << 8) | (b2 << 16) | (b3 << 24);
  }
  int4v o = {(int)w[0], (int)w[1], (int)w[2], (int)w[3]};
  *(int4v*)(Bt + (size_t)(n0 + nr) * K_DIM + (k0 + kb)) = o;
}

// colsum of B' = rowsum of Bt
__global__ __launch_bounds__(256) void colsum_k(const signed char* __restrict__ Bt,
                                                int* __restrict__ colsum) {
  const int n = blockIdx.x, t = threadIdx.x;
  const int4v v = ((const int4v*)(Bt + (size_t)n * K_DIM))[t];
  int sum = 0;
#pragma unroll
  for (int c = 0; c < 4; c++) {
    unsigned w = (unsigned)v[c];
    sum += (int)(signed char)(w & 255u) + (int)(signed char)((w >> 8) & 255u) +
           (int)(signed char)((w >> 16) & 255u) + (int)(signed char)((w >> 24) & 255u);
  }
  for (int off = 32; off; off >>= 1) sum += __shfl_down(sum, off);
  __shared__ int sw[4];
  if ((t & 63) == 0) sw[t >> 6] = sum;
  __syncthreads();
  if (t == 0) colsum[n] = sw[0] + sw[1] + sw[2] + sw[3];
}

// ---- i8 GEMM: 256x128 tile, BK=64, 8 waves (2M x 4N), wave = 128x32 ----
// LDS slot = A 16KiB (64 pseudo-rows x 256B) + B 8KiB (32 pseudo-rows x 256B).
// Pseudo-row R packs rows 4R..4R+3; 16B block at (4c+lb) ^ (R&7).
__global__ __launch_bounds__(512, 4) void gemm_k(const signed char* __restrict__ Aq,
                                                 const signed char* __restrict__ Bt,
                                                 float* __restrict__ C,
                                                 const int* __restrict__ rowsum,
                                                 const int* __restrict__ colsum,
                                                 const unsigned* __restrict__ mm) {
  __shared__ signed char lds[49152];   // 2 slots x 24 KiB
  const int t = threadIdx.x;

  // XCD-bijective swizzle: 2048 wgs, 8 XCDs, 256/XCD; n walks fastest (A-panel L2 reuse)
  const int orig = blockIdx.x;
  const int wgid = (orig & 7) * 256 + (orig >> 3);
  const int m0 = (wgid >> 5) * 256;
  const int n0 = (wgid & 31) * 128;

  const int w = t >> 6, l = t & 63;
  const int wm = (w >> 2) * 128;        // 2 wave-rows of 128
  const int wn = (w & 3) * 32;          // 4 wave-cols of 32
  const int r32 = l & 31, h = l >> 5;
  const int u = r32 >> 2, c4 = (r32 & 3) * 4;

  // tile-invariant LDS read addresses (slot 0); slot 1 = +24576 (imm offset)
  unsigned aAddr[4][2], bAddr[2];
#pragma unroll
  for (int m = 0; m < 4; ++m)
#pragma unroll
    for (int kk = 0; kk < 2; ++kk)
      aAddr[m][kk] = (unsigned)(((wm + 32 * m) >> 2) + u) * 256 +
                     (unsigned)(((c4 + 2 * kk + h) ^ u) << 4);
#pragma unroll
  for (int kk = 0; kk < 2; ++kk)
    bAddr[kk] = 16384u + (unsigned)(8 * (w & 3) + u) * 256 +
                (unsigned)(((c4 + 2 * kk + h) ^ u) << 4);

  // staging: per-lane pre-swizzled global source, lane-linear LDS dest.
  // LDS pos t*16 -> pseudo-row Rq=t>>4, slot bs=t&15; (row,lb) = inverse swizzle.
  const int bs_ = t & 15, Rq = t >> 4;
  const int b16 = bs_ ^ (Rq & 7);
  const int sc = b16 >> 2, slb = b16 & 3;
  const signed char* pA0 = Aq + (size_t)(m0 + 4 * Rq + sc) * K_DIM + slb * 16;
  const signed char* pA1 = pA0 + (size_t)128 * K_DIM;
  const signed char* pB  = Bt + (size_t)(n0 + 4 * Rq + sc) * K_DIM + slb * 16;

  int16v acc[4] = {};

#define STAGE(NXT) do {                                   \
    gload16(pA0, lds + (NXT) + t * 16);                   \
    gload16(pA1, lds + (NXT) + 8192 + t * 16);            \
    gload16(pB,  lds + (NXT) + 16384 + t * 16);           \
    pA0 += 64; pA1 += 64; pB += 64; } while (0)

#define MFMA4(A0, A1, A2, A3, B0)                                            \
    __builtin_amdgcn_s_setprio(1);                                           \
    acc[0] = __builtin_amdgcn_mfma_i32_32x32x32_i8(A0, B0, acc[0], 0, 0, 0); \
    acc[1] = __builtin_amdgcn_mfma_i32_32x32x32_i8(A1, B0, acc[1], 0, 0, 0); \
    acc[2] = __builtin_amdgcn_mfma_i32_32x32x32_i8(A2, B0, acc[2], 0, 0, 0); \
    acc[3] = __builtin_amdgcn_mfma_i32_32x32x32_i8(A3, B0, acc[3], 0, 0, 0); \
    __builtin_amdgcn_s_setprio(0);

#define COMP(CUR) do {                                                \
    int4v b0 = *(const int4v*)(lds + (CUR) + bAddr[0]);               \
    int4v a0 = *(const int4v*)(lds + (CUR) + aAddr[0][0]);            \
    int4v a1 = *(const int4v*)(lds + (CUR) + aAddr[1][0]);            \
    int4v a2 = *(const int4v*)(lds + (CUR) + aAddr[2][0]);            \
    int4v a3 = *(const int4v*)(lds + (CUR) + aAddr[3][0]);            \
    MFMA4(a0, a1, a2, a3, b0)                                         \
    b0 = *(const int4v*)(lds + (CUR) + bAddr[1]);                     \
    a0 = *(const int4v*)(lds + (CUR) + aAddr[0][1]);                  \
    a1 = *(const int4v*)(lds + (CUR) + aAddr[1][1]);                  \
    a2 = *(const int4v*)(lds + (CUR) + aAddr[2][1]);                  \
    a3 = *(const int4v*)(lds + (CUR) + aAddr[3][1]);                  \
    MFMA4(a0, a1, a2, a3, b0)                                         \
  } while (0)

  // prologue: stage tile 0 -> slot 0
  STAGE(0);
  __syncthreads();

#pragma unroll 1
  for (int it = 0; it < 31; ++it) {
    STAGE(24576); COMP(0);     __syncthreads();
    STAGE(0);     COMP(24576); __syncthreads();
  }
  STAGE(24576); COMP(0); __syncthreads();
  COMP(24576);

#undef STAGE
#undef MFMA4
#undef COMP

  // epilogue: integer zero-point corrections (exact), then scale.
  // C/D layout (32x32): col = lane&31, row = (reg&3) + 8*(reg>>2) + 4*(lane>>5)
  const float amin = dec_f(mm[0]), amax = dec_f(mm[1]);
  const float bmin = dec_f(mm[2]), bmax = dec_f(mm[3]);
  const float sa = fmaxf((amax - amin) / 255.0f, 1e-8f);
  const float sb = fmaxf((bmax - bmin) / 255.0f, 1e-8f);
  const int za = (int)rintf(-amin / sa) - 128;
  const int zb = (int)rintf(-bmin / sb) - 128;
  const float sab = sa * sb;
  const int kzz = K_DIM * za * zb;
  const int col = n0 + wn + r32;
  const int cs = za * colsum[col];
#pragma unroll
  for (int m = 0; m < 4; ++m) {
    const int rbase = m0 + wm + m * 32 + 4 * h;
#pragma unroll
    for (int r = 0; r < 16; ++r) {
      const int row = rbase + (r & 3) + 8 * (r >> 2);
      const int v = acc[m][r] - zb * rowsum[row] - cs + kzz;
      C[(size_t)row * N_COLS + col] = sab * (float)v;
    }
  }
}

extern "C" void kernel_launch(void* const* d_in, const int* in_sizes, int n_in,
                              void* d_out, int out_size, void* d_ws, size_t ws_size,
                              hipStream_t stream) {
  const float* A = (const float*)d_in[0];
  const float* B = (const float*)d_in[1];
  float* C = (float*)d_out;
  char* ws = (char*)d_ws;
  signed char* Aq = (signed char*)(ws + OFF_AQ);
  signed char* Bt = (signed char*)(ws + OFF_BT);
  int* rowsum = (int*)(ws + OFF_RS);
  int* colsum = (int*)(ws + OFF_CS);
  unsigned* mm = (unsigned*)(ws + OFF_MM);

  init_mm_k<<<1, 64, 0, stream>>>(mm);
  minmax_k<<<5120, 256, 0, stream>>>((const float4*)A, (const float4*)B, mm);
  quantA_k<<<M_ROWS, 256, 0, stream>>>(A, Aq, rowsum, mm);
  quantB_k<<<dim3(64, 64), 256, 0, stream>>>(B, Bt, mm);
  colsum_k<<<N_COLS, 256, 0, stream>>>(Bt, colsum);
  gemm_k<<<2048, 512, 0, stream>>>(Aq, Bt, C, rowsum, colsum, mm);
}

// Round 3
// 881.959 us; speedup vs baseline: 1.0142x; 1.0142x over previous
//
#include <hip/hip_runtime.h>

// QuantMatMul: fake-quant(A) @ fake-quant(B), computed exactly via i8 MFMA.
// A: [4,4096,4096] fp32 -> folded to M=16384 rows. B: [4096,4096] fp32 (K x N).
// C = s_a*s_b * ( A'B' - zb*rowsumA[m] - za*colsumB[n] + K*za*zb ),  A',B' in i8.
//
// Round 5: 256x128 tile, BK=64, 512 threads / 8 waves as 4Mx2N of 64x64
// (acc[2][2]); 3-slot LDS rotation (3x24KiB=72KiB) with prefetch distance 2 and
// COUNTED vmcnt (T4): per tile { s_waitcnt vmcnt(3); s_barrier; sched_barrier;
// STAGE(t+2); COMP(t) } -- vmcnt never drains to 0 in the main loop, one
// barrier per tile. Per-lane pre-swizzled global source -> lane-linear LDS dest
// (conflict-free reads, verified 0 conflicts in R4). colsum fused into quantB.

#define K_DIM 4096
#define N_COLS 4096
#define M_ROWS 16384

typedef __attribute__((ext_vector_type(4))) int int4v;
typedef __attribute__((ext_vector_type(16))) int int16v;

// ---- workspace layout ----
static const size_t OFF_AQ = 0;                                  // 64 MiB  i8 [16384][4096] (plain)
static const size_t OFF_BT = (size_t)64 << 20;                   // 16 MiB  i8 [4096][4096] (B^T, plain)
static const size_t OFF_RS = OFF_BT + ((size_t)16 << 20);        // 64 KiB  int rowsumA
static const size_t OFF_CS = OFF_RS + (size_t)M_ROWS * 4;        // 16 KiB  int colsumB
static const size_t OFF_MM = OFF_CS + (size_t)N_COLS * 4;        // 64 B    minmax enc

// sortable encoding for float atomic min/max
__device__ __forceinline__ unsigned enc_f(float f) {
  unsigned u = __float_as_uint(f);
  return (u & 0x80000000u) ? ~u : (u | 0x80000000u);
}
__device__ __forceinline__ float dec_f(unsigned e) {
  unsigned u = (e & 0x80000000u) ? (e & 0x7fffffffu) : ~e;
  return __uint_as_float(u);
}

// reciprocal-multiply quantize: matches ref's clip(rint(x/s)+zp,0,255), -128 shift
__device__ __forceinline__ int quantize1(float x, float r, float zp) {
  return (int)(fminf(fmaxf(rintf(x * r) + zp, 0.0f), 255.0f)) - 128;
}

__device__ __forceinline__ void gload16(const void* g, void* l) {
  __builtin_amdgcn_global_load_lds(
      (const __attribute__((address_space(1))) unsigned int*)g,
      (__attribute__((address_space(3))) unsigned int*)l, 16, 0, 0);
}

// per-block inline param computation (deterministic; identical fp ops everywhere)
__device__ __forceinline__ void qparams_a(const unsigned* mm, float& ra, float& zpa) {
  const float amin = dec_f(mm[0]), amax = dec_f(mm[1]);
  const float sa = fmaxf((amax - amin) / 255.0f, 1e-8f);
  zpa = rintf(-amin / sa);
  ra = 1.0f / sa;
}
__device__ __forceinline__ void qparams_b(const unsigned* mm, float& rb, float& zpb) {
  const float bmin = dec_f(mm[2]), bmax = dec_f(mm[3]);
  const float sb = fmaxf((bmax - bmin) / 255.0f, 1e-8f);
  zpb = rintf(-bmin / sb);
  rb = 1.0f / sb;
}

// init: minmax sentinels + zero colsum (quantB accumulates into it atomically)
__global__ __launch_bounds__(256) void init_k(unsigned* __restrict__ mm,
                                              int* __restrict__ colsum) {
  const int i = blockIdx.x * 256 + threadIdx.x;
  if (i < N_COLS) colsum[i] = 0;
  if (i == N_COLS) {
    mm[0] = 0xFFFFFFFFu; mm[1] = 0u;   // A min/max (encoded)
    mm[2] = 0xFFFFFFFFu; mm[3] = 0u;   // B min/max
  }
}

// fused minmax over A (blocks 0..4095) and B (blocks 4096..5119)
__global__ __launch_bounds__(256) void minmax_k(const float4* __restrict__ A,
                                                const float4* __restrict__ B,
                                                unsigned* __restrict__ mm) {
  const bool isB = blockIdx.x >= 4096;
  const float4* __restrict__ x = isB ? B : A;
  const long n4 = isB ? (long)K_DIM * N_COLS / 4 : (long)M_ROWS * K_DIM / 4;
  const int nblk = isB ? 1024 : 4096;
  const int bid = isB ? (int)blockIdx.x - 4096 : (int)blockIdx.x;
  unsigned* m = mm + (isB ? 2 : 0);

  float lo = 3.402823466e38f, hi = -3.402823466e38f;
  long i = (long)bid * blockDim.x + threadIdx.x;
  const long stride = (long)nblk * blockDim.x;
  for (; i < n4; i += stride) {
    float4 v = x[i];
    lo = fminf(lo, fminf(fminf(v.x, v.y), fminf(v.z, v.w)));
    hi = fmaxf(hi, fmaxf(fmaxf(v.x, v.y), fmaxf(v.z, v.w)));
  }
  for (int off = 32; off; off >>= 1) {
    lo = fminf(lo, __shfl_down(lo, off));
    hi = fmaxf(hi, __shfl_down(hi, off));
  }
  __shared__ float slo[4], shi[4];
  const int t = threadIdx.x;
  if ((t & 63) == 0) { slo[t >> 6] = lo; shi[t >> 6] = hi; }
  __syncthreads();
  if (t == 0) {
    for (int w = 1; w < 4; w++) { lo = fminf(lo, slo[w]); hi = fmaxf(hi, shi[w]); }
    atomicMin(&m[0], enc_f(lo));
    atomicMax(&m[1], enc_f(hi));
  }
}

// one block per row: quantize (plain coalesced layout) + rowsum
__global__ __launch_bounds__(256) void quantA_k(const float* __restrict__ A,
                                                signed char* __restrict__ Aq,
                                                int* __restrict__ rowsum,
                                                const unsigned* __restrict__ mm) {
  float ra, zpa;
  qparams_a(mm, ra, zpa);
  const int row = blockIdx.x, t = threadIdx.x;
  const float4* src = (const float4*)(A + (size_t)row * K_DIM);
  unsigned* dst = (unsigned*)(Aq + (size_t)row * K_DIM);
  int sum = 0;
#pragma unroll
  for (int j = 0; j < 4; j++) {
    const int d = j * 256 + t;           // dword index in row (0..1023)
    float4 v = src[d];
    int q0 = quantize1(v.x, ra, zpa);
    int q1 = quantize1(v.y, ra, zpa);
    int q2 = quantize1(v.z, ra, zpa);
    int q3 = quantize1(v.w, ra, zpa);
    sum += q0 + q1 + q2 + q3;
    dst[d] = ((unsigned)q0 & 255u) | (((unsigned)q1 & 255u) << 8) |
             (((unsigned)q2 & 255u) << 16) | (((unsigned)q3 & 255u) << 24);
  }
  for (int off = 32; off; off >>= 1) sum += __shfl_down(sum, off);
  __shared__ int sw[4];
  if ((t & 63) == 0) sw[t >> 6] = sum;
  __syncthreads();
  if (t == 0) rowsum[row] = sw[0] + sw[1] + sw[2] + sw[3];
}

// quantize B, transpose to Bt[N][K] via 64x64 LDS tile; fused colsum via
// exact integer atomics (order-independent -> deterministic)
__global__ __launch_bounds__(256) void quantB_k(const float* __restrict__ B,
                                                signed char* __restrict__ Bt,
                                                int* __restrict__ colsum,
                                                const unsigned* __restrict__ mm) {
  float rb, zpb;
  qparams_b(mm, rb, zpb);
  __shared__ unsigned char s[64][72];
  const int n0 = blockIdx.x * 64, k0 = blockIdx.y * 64;
  const int t = threadIdx.x;
  const int kr = t >> 2, tl = t & 3;
  const float* rowp = B + (size_t)(k0 + kr) * N_COLS + n0;
#pragma unroll
  for (int j = 0; j < 4; j++) {
    const int fi = tl + j * 4;
    float4 v = *(const float4*)(rowp + fi * 4);
    int q0 = quantize1(v.x, rb, zpb);
    int q1 = quantize1(v.y, rb, zpb);
    int q2 = quantize1(v.z, rb, zpb);
    int q3 = quantize1(v.w, rb, zpb);
    *(unsigned*)&s[kr][fi * 4] = ((unsigned)q0 & 255u) | (((unsigned)q1 & 255u) << 8) |
                                 (((unsigned)q2 & 255u) << 16) | (((unsigned)q3 & 255u) << 24);
  }
  __syncthreads();
  const int nr = t >> 2;                 // output row within tile (n)
  const int kb = tl * 16;                // 16-byte K block within 64B chunk
  unsigned w[4];
  int psum = 0;
#pragma unroll
  for (int jj = 0; jj < 4; jj++) {
    unsigned b0 = s[kb + jj * 4 + 0][nr];
    unsigned b1 = s[kb + jj * 4 + 1][nr];
    unsigned b2 = s[kb + jj * 4 + 2][nr];
    unsigned b3 = s[kb + jj * 4 + 3][nr];
    w[jj] = b0 | (b1 << 8) | (b2 << 16) | (b3 << 24);
    psum += (int)(signed char)b0 + (int)(signed char)b1 +
            (int)(signed char)b2 + (int)(signed char)b3;
  }
  int4v o = {(int)w[0], (int)w[1], (int)w[2], (int)w[3]};
  *(int4v*)(Bt + (size_t)(n0 + nr) * K_DIM + (k0 + kb)) = o;
  // reduce 4 lanes (tl=0..3) holding the same output row nr, then one atomic
  psum += __shfl_xor(psum, 1);
  psum += __shfl_xor(psum, 2);
  if (tl == 0) atomicAdd(&colsum[n0 + nr], psum);
}

// ---- i8 GEMM: 256x128 tile, BK=64, 8 waves (4M x 2N), wave = 64x64 ----
// LDS slot = A 16KiB (64 pseudo-rows x 256B) + B 8KiB (32 pseudo-rows x 256B).
// Pseudo-row R packs rows 4R..4R+3; 16B block at index g stored at g ^ (R&7).
__global__ __launch_bounds__(512, 4) void gemm_k(const signed char* __restrict__ Aq,
                                                 const signed char* __restrict__ Bt,
                                                 float* __restrict__ C,
                                                 const int* __restrict__ rowsum,
                                                 const int* __restrict__ colsum,
                                                 const unsigned* __restrict__ mm) {
  __shared__ signed char lds[73728];   // 3 slots x 24 KiB
  const int t = threadIdx.x;

  // XCD-bijective swizzle: 2048 wgs, 8 XCDs, 256/XCD; n walks fastest
  const int orig = blockIdx.x;
  const int wgid = (orig & 7) * 256 + (orig >> 3);
  const int m0 = (wgid >> 5) * 256;
  const int n0 = (wgid & 31) * 128;

  const int w = t >> 6, l = t & 63;
  const int wm16 = (w >> 1) * 16;       // (wave m-offset)/4 : waves 4M
  const int wn16 = (w & 1) * 16;        // (wave n-offset)/4 : waves 2N
  const int r32 = l & 31, h = l >> 5;
  const int u = r32 >> 2, c4 = (r32 & 3) * 4;

  // tile-invariant LDS read addresses (slot-relative)
  unsigned aAddr[2][2], bAddr[2][2];
#pragma unroll
  for (int mi = 0; mi < 2; ++mi)
#pragma unroll
    for (int kk = 0; kk < 2; ++kk)
      aAddr[mi][kk] = (unsigned)(wm16 + 8 * mi + u) * 256 +
                      ((unsigned)((c4 + 2 * kk + h) ^ u) << 4);
#pragma unroll
  for (int ni = 0; ni < 2; ++ni)
#pragma unroll
    for (int kk = 0; kk < 2; ++kk)
      bAddr[ni][kk] = 16384u + (unsigned)(wn16 + 8 * ni + u) * 256 +
                      ((unsigned)((c4 + 2 * kk + h) ^ u) << 4);

  // staging: per-lane pre-swizzled global source, lane-linear LDS dest.
  const int bs_ = t & 15, Rq = t >> 4;
  const int b16 = bs_ ^ (Rq & 7);
  const int sc = b16 >> 2, slb = b16 & 3;
  const signed char* pA0 = Aq + (size_t)(m0 + 4 * Rq + sc) * K_DIM + slb * 16;
  const signed char* pA1 = pA0 + (size_t)128 * K_DIM;
  const signed char* pB  = Bt + (size_t)(n0 + 4 * Rq + sc) * K_DIM + slb * 16;

  int16v acc[2][2] = {};

#define STAGE(SO) do {                                    \
    gload16(pA0, lds + (SO) + t * 16);                    \
    gload16(pA1, lds + (SO) + 8192 + t * 16);             \
    gload16(pB,  lds + (SO) + 16384 + t * 16);            \
    pA0 += 64; pA1 += 64; pB += 64; } while (0)

#define MM_(A, B, CC) CC = __builtin_amdgcn_mfma_i32_32x32x32_i8(A, B, CC, 0, 0, 0)

#define COMP(SO) do {                                                 \
    int4v b0 = *(const int4v*)(lds + (SO) + bAddr[0][0]);             \
    int4v b1 = *(const int4v*)(lds + (SO) + bAddr[1][0]);             \
    int4v a0 = *(const int4v*)(lds + (SO) + aAddr[0][0]);             \
    int4v a1 = *(const int4v*)(lds + (SO) + aAddr[1][0]);             \
    __builtin_amdgcn_s_setprio(1);                                    \
    MM_(a0, b0, acc[0][0]); MM_(a0, b1, acc[0][1]);                   \
    MM_(a1, b0, acc[1][0]); MM_(a1, b1, acc[1][1]);                   \
    __builtin_amdgcn_s_setprio(0);                                    \
    b0 = *(const int4v*)(lds + (SO) + bAddr[0][1]);                   \
    b1 = *(const int4v*)(lds + (SO) + bAddr[1][1]);                   \
    a0 = *(const int4v*)(lds + (SO) + aAddr[0][1]);                   \
    a1 = *(const int4v*)(lds + (SO) + aAddr[1][1]);                   \
    __builtin_amdgcn_s_setprio(1);                                    \
    MM_(a0, b0, acc[0][0]); MM_(a0, b1, acc[0][1]);                   \
    MM_(a1, b0, acc[1][0]); MM_(a1, b1, acc[1][1]);                   \
    __builtin_amdgcn_s_setprio(0);                                    \
  } while (0)

#define WAITN(N) asm volatile("s_waitcnt vmcnt(" #N ")" ::: "memory")
#define BARR do { __builtin_amdgcn_s_barrier();                       \
                  __builtin_amdgcn_sched_barrier(0); } while (0)

  // ITER(t): wait tile-t loads (keep t+1 in flight), join, stage t+2, compute t
#define ITER(SC, SN) do { WAITN(3); BARR; STAGE(SN); COMP(SC); } while (0)

  // prologue: stage tiles 0 and 1
  STAGE(0);
  STAGE(24576);

#pragma unroll 1
  for (int g = 0; g < 20; ++g) {       // t = 3g .. 3g+2  (0..59)
    ITER(0, 49152);
    ITER(24576, 0);
    ITER(49152, 24576);
  }
  ITER(0, 49152);                      // t = 60 (stages 62)
  ITER(24576, 0);                      // t = 61 (stages 63)
  WAITN(3); BARR; COMP(49152);         // t = 62 (63 still in flight)
  WAITN(0); BARR; COMP(0);             // t = 63

#undef STAGE
#undef MM_
#undef COMP
#undef WAITN
#undef BARR
#undef ITER

  // epilogue: integer zero-point corrections (exact), then scale.
  // C/D layout (32x32): col = lane&31, row = (reg&3) + 8*(reg>>2) + 4*(lane>>5)
  const float amin = dec_f(mm[0]), amax = dec_f(mm[1]);
  const float bmin = dec_f(mm[2]), bmax = dec_f(mm[3]);
  const float sa = fmaxf((amax - amin) / 255.0f, 1e-8f);
  const float sb = fmaxf((bmax - bmin) / 255.0f, 1e-8f);
  const int za = (int)rintf(-amin / sa) - 128;
  const int zb = (int)rintf(-bmin / sb) - 128;
  const float sab = sa * sb;
  const int kzz = K_DIM * za * zb;
  const int wm = wm16 * 4, wn = wn16 * 4;
  const int col0 = n0 + wn + r32;
  const int cs0 = za * colsum[col0];
  const int cs1 = za * colsum[col0 + 32];
#pragma unroll
  for (int mi = 0; mi < 2; ++mi) {
    const int rbase = m0 + wm + mi * 32 + 4 * h;
#pragma unroll
    for (int r = 0; r < 16; ++r) {
      const int row = rbase + (r & 3) + 8 * (r >> 2);
      const int base = kzz - zb * rowsum[row];
      C[(size_t)row * N_COLS + col0]      = sab * (float)(acc[mi][0][r] + base - cs0);
      C[(size_t)row * N_COLS + col0 + 32] = sab * (float)(acc[mi][1][r] + base - cs1);
    }
  }
}

extern "C" void kernel_launch(void* const* d_in, const int* in_sizes, int n_in,
                              void* d_out, int out_size, void* d_ws, size_t ws_size,
                              hipStream_t stream) {
  const float* A = (const float*)d_in[0];
  const float* B = (const float*)d_in[1];
  float* C = (float*)d_out;
  char* ws = (char*)d_ws;
  signed char* Aq = (signed char*)(ws + OFF_AQ);
  signed char* Bt = (signed char*)(ws + OFF_BT);
  int* rowsum = (int*)(ws + OFF_RS);
  int* colsum = (int*)(ws + OFF_CS);
  unsigned* mm = (unsigned*)(ws + OFF_MM);

  init_k<<<17, 256, 0, stream>>>(mm, colsum);
  minmax_k<<<5120, 256, 0, stream>>>((const float4*)A, (const float4*)B, mm);
  quantA_k<<<M_ROWS, 256, 0, stream>>>(A, Aq, rowsum, mm);
  quantB_k<<<dim3(64, 64), 256, 0, stream>>>(B, Bt, colsum, mm);
  gemm_k<<<2048, 512, 0, stream>>>(Aq, Bt, C, rowsum, colsum, mm);
}

// Round 4
// 864.872 us; speedup vs baseline: 1.0343x; 1.0198x over previous
//
#include <hip/hip_runtime.h>

// QuantMatMul: fake-quant(A) @ fake-quant(B), computed exactly via i8 MFMA.
// A: [4,4096,4096] fp32 -> folded to M=16384 rows. B: [4096,4096] fp32 (K x N).
// C = s_a*s_b * ( A'B' - zb*rowsumA[m] - za*colsumB[n] + K*za*zb ),  A',B' in i8.
//
// Round 6: LDS-traffic cut. 256x128 tile, BK=64, 256 threads / 4 waves (2Mx2N)
// of 128x64 (acc[4][2], 128 AGPR): 12 B/lane/MFMA LDS reads (75% of ceiling)
// vs R5's 16 B (100%+). 3-slot LDS rotation (3x24KiB), distance-2 prefetch,
// counted vmcnt(6) (never 0 in main loop), ONE barrier per tile. 2 blocks/CU
// resident (independent schedules de-convoy). Per-lane pre-swizzled global
// source -> lane-linear LDS dest (0 bank conflicts, verified R4/R5).

#define K_DIM 4096
#define N_COLS 4096
#define M_ROWS 16384

typedef __attribute__((ext_vector_type(4))) int int4v;
typedef __attribute__((ext_vector_type(16))) int int16v;

// ---- workspace layout ----
static const size_t OFF_AQ = 0;                                  // 64 MiB  i8 [16384][4096] (plain)
static const size_t OFF_BT = (size_t)64 << 20;                   // 16 MiB  i8 [4096][4096] (B^T, plain)
static const size_t OFF_RS = OFF_BT + ((size_t)16 << 20);        // 64 KiB  int rowsumA
static const size_t OFF_CS = OFF_RS + (size_t)M_ROWS * 4;        // 16 KiB  int colsumB
static const size_t OFF_MM = OFF_CS + (size_t)N_COLS * 4;        // 64 B    minmax enc

// sortable encoding for float atomic min/max
__device__ __forceinline__ unsigned enc_f(float f) {
  unsigned u = __float_as_uint(f);
  return (u & 0x80000000u) ? ~u : (u | 0x80000000u);
}
__device__ __forceinline__ float dec_f(unsigned e) {
  unsigned u = (e & 0x80000000u) ? (e & 0x7fffffffu) : ~e;
  return __uint_as_float(u);
}

// reciprocal-multiply quantize: matches ref's clip(rint(x/s)+zp,0,255), -128 shift
__device__ __forceinline__ int quantize1(float x, float r, float zp) {
  return (int)(fminf(fmaxf(rintf(x * r) + zp, 0.0f), 255.0f)) - 128;
}

__device__ __forceinline__ void gload16(const void* g, void* l) {
  __builtin_amdgcn_global_load_lds(
      (const __attribute__((address_space(1))) unsigned int*)g,
      (__attribute__((address_space(3))) unsigned int*)l, 16, 0, 0);
}

// per-block inline param computation (deterministic; identical fp ops everywhere)
__device__ __forceinline__ void qparams_a(const unsigned* mm, float& ra, float& zpa) {
  const float amin = dec_f(mm[0]), amax = dec_f(mm[1]);
  const float sa = fmaxf((amax - amin) / 255.0f, 1e-8f);
  zpa = rintf(-amin / sa);
  ra = 1.0f / sa;
}
__device__ __forceinline__ void qparams_b(const unsigned* mm, float& rb, float& zpb) {
  const float bmin = dec_f(mm[2]), bmax = dec_f(mm[3]);
  const float sb = fmaxf((bmax - bmin) / 255.0f, 1e-8f);
  zpb = rintf(-bmin / sb);
  rb = 1.0f / sb;
}

// init: minmax sentinels + zero colsum (quantB accumulates into it atomically)
__global__ __launch_bounds__(256) void init_k(unsigned* __restrict__ mm,
                                              int* __restrict__ colsum) {
  const int i = blockIdx.x * 256 + threadIdx.x;
  if (i < N_COLS) colsum[i] = 0;
  if (i == N_COLS) {
    mm[0] = 0xFFFFFFFFu; mm[1] = 0u;   // A min/max (encoded)
    mm[2] = 0xFFFFFFFFu; mm[3] = 0u;   // B min/max
  }
}

// fused minmax over A (blocks 0..4095) and B (blocks 4096..5119)
__global__ __launch_bounds__(256) void minmax_k(const float4* __restrict__ A,
                                                const float4* __restrict__ B,
                                                unsigned* __restrict__ mm) {
  const bool isB = blockIdx.x >= 4096;
  const float4* __restrict__ x = isB ? B : A;
  const long n4 = isB ? (long)K_DIM * N_COLS / 4 : (long)M_ROWS * K_DIM / 4;
  const int nblk = isB ? 1024 : 4096;
  const int bid = isB ? (int)blockIdx.x - 4096 : (int)blockIdx.x;
  unsigned* m = mm + (isB ? 2 : 0);

  float lo = 3.402823466e38f, hi = -3.402823466e38f;
  long i = (long)bid * blockDim.x + threadIdx.x;
  const long stride = (long)nblk * blockDim.x;
  for (; i < n4; i += stride) {
    float4 v = x[i];
    lo = fminf(lo, fminf(fminf(v.x, v.y), fminf(v.z, v.w)));
    hi = fmaxf(hi, fmaxf(fmaxf(v.x, v.y), fmaxf(v.z, v.w)));
  }
  for (int off = 32; off; off >>= 1) {
    lo = fminf(lo, __shfl_down(lo, off));
    hi = fmaxf(hi, __shfl_down(hi, off));
  }
  __shared__ float slo[4], shi[4];
  const int t = threadIdx.x;
  if ((t & 63) == 0) { slo[t >> 6] = lo; shi[t >> 6] = hi; }
  __syncthreads();
  if (t == 0) {
    for (int w = 1; w < 4; w++) { lo = fminf(lo, slo[w]); hi = fmaxf(hi, shi[w]); }
    atomicMin(&m[0], enc_f(lo));
    atomicMax(&m[1], enc_f(hi));
  }
}

// one block per row: quantize (plain coalesced layout) + rowsum
__global__ __launch_bounds__(256) void quantA_k(const float* __restrict__ A,
                                                signed char* __restrict__ Aq,
                                                int* __restrict__ rowsum,
                                                const unsigned* __restrict__ mm) {
  float ra, zpa;
  qparams_a(mm, ra, zpa);
  const int row = blockIdx.x, t = threadIdx.x;
  const float4* src = (const float4*)(A + (size_t)row * K_DIM);
  unsigned* dst = (unsigned*)(Aq + (size_t)row * K_DIM);
  int sum = 0;
#pragma unroll
  for (int j = 0; j < 4; j++) {
    const int d = j * 256 + t;           // dword index in row (0..1023)
    float4 v = src[d];
    int q0 = quantize1(v.x, ra, zpa);
    int q1 = quantize1(v.y, ra, zpa);
    int q2 = quantize1(v.z, ra, zpa);
    int q3 = quantize1(v.w, ra, zpa);
    sum += q0 + q1 + q2 + q3;
    dst[d] = ((unsigned)q0 & 255u) | (((unsigned)q1 & 255u) << 8) |
             (((unsigned)q2 & 255u) << 16) | (((unsigned)q3 & 255u) << 24);
  }
  for (int off = 32; off; off >>= 1) sum += __shfl_down(sum, off);
  __shared__ int sw[4];
  if ((t & 63) == 0) sw[t >> 6] = sum;
  __syncthreads();
  if (t == 0) rowsum[row] = sw[0] + sw[1] + sw[2] + sw[3];
}

// quantize B, transpose to Bt[N][K] via 64x64 LDS tile; fused colsum via
// exact integer atomics (order-independent -> deterministic)
__global__ __launch_bounds__(256) void quantB_k(const float* __restrict__ B,
                                                signed char* __restrict__ Bt,
                                                int* __restrict__ colsum,
                                                const unsigned* __restrict__ mm) {
  float rb, zpb;
  qparams_b(mm, rb, zpb);
  __shared__ unsigned char s[64][72];
  const int n0 = blockIdx.x * 64, k0 = blockIdx.y * 64;
  const int t = threadIdx.x;
  const int kr = t >> 2, tl = t & 3;
  const float* rowp = B + (size_t)(k0 + kr) * N_COLS + n0;
#pragma unroll
  for (int j = 0; j < 4; j++) {
    const int fi = tl + j * 4;
    float4 v = *(const float4*)(rowp + fi * 4);
    int q0 = quantize1(v.x, rb, zpb);
    int q1 = quantize1(v.y, rb, zpb);
    int q2 = quantize1(v.z, rb, zpb);
    int q3 = quantize1(v.w, rb, zpb);
    *(unsigned*)&s[kr][fi * 4] = ((unsigned)q0 & 255u) | (((unsigned)q1 & 255u) << 8) |
                                 (((unsigned)q2 & 255u) << 16) | (((unsigned)q3 & 255u) << 24);
  }
  __syncthreads();
  const int nr = t >> 2;                 // output row within tile (n)
  const int kb = tl * 16;                // 16-byte K block within 64B chunk
  unsigned w[4];
  int psum = 0;
#pragma unroll
  for (int jj = 0; jj < 4; jj++) {
    unsigned b0 = s[kb + jj * 4 + 0][nr];
    unsigned b1 = s[kb + jj * 4 + 1][nr];
    unsigned b2 = s[kb + jj * 4 + 2][nr];
    unsigned b3 = s[kb + jj * 4 + 3][nr];
    w[jj] = b0 | (b1 << 8) | (b2 << 16) | (b3 << 24);
    psum += (int)(signed char)b0 + (int)(signed char)b1 +
            (int)(signed char)b2 + (int)(signed char)b3;
  }
  int4v o = {(int)w[0], (int)w[1], (int)w[2], (int)w[3]};
  *(int4v*)(Bt + (size_t)(n0 + nr) * K_DIM + (k0 + kb)) = o;
  // reduce 4 lanes (tl=0..3) holding the same output row nr, then one atomic
  psum += __shfl_xor(psum, 1);
  psum += __shfl_xor(psum, 2);
  if (tl == 0) atomicAdd(&colsum[n0 + nr], psum);
}

// ---- i8 GEMM: 256x128 tile, BK=64, 4 waves (2M x 2N), wave = 128x64 ----
// LDS slot = A 16KiB (64 pseudo-rows x 256B) + B 8KiB (32 pseudo-rows x 256B).
// Pseudo-row R packs rows 4R..4R+3; 16B block at index g stored at g ^ (R&7).
__global__ __launch_bounds__(256, 2) void gemm_k(const signed char* __restrict__ Aq,
                                                 const signed char* __restrict__ Bt,
                                                 float* __restrict__ C,
                                                 const int* __restrict__ rowsum,
                                                 const int* __restrict__ colsum,
                                                 const unsigned* __restrict__ mm) {
  __shared__ signed char lds[73728];   // 3 slots x 24 KiB
  const int t = threadIdx.x;

  // XCD-bijective swizzle: 2048 wgs, 8 XCDs, 256/XCD; n walks fastest
  const int orig = blockIdx.x;
  const int wgid = (orig & 7) * 256 + (orig >> 3);
  const int m0 = (wgid >> 5) * 256;
  const int n0 = (wgid & 31) * 128;

  const int w = t >> 6, l = t & 63;
  const int wm4 = (w >> 1) * 32;        // (wave m-offset)/4 : 2M waves of 128 rows
  const int wn4 = (w & 1) * 16;         // (wave n-offset)/4 : 2N waves of 64 cols
  const int r32 = l & 31, h = l >> 5;
  const int u = r32 >> 2, c4 = (r32 & 3) * 4;

  // tile-invariant LDS read addresses (slot-relative)
  unsigned aAddr[4][2], bAddr[2][2];
#pragma unroll
  for (int mi = 0; mi < 4; ++mi)
#pragma unroll
    for (int kk = 0; kk < 2; ++kk)
      aAddr[mi][kk] = (unsigned)(wm4 + 8 * mi + u) * 256 +
                      ((unsigned)((c4 + 2 * kk + h) ^ u) << 4);
#pragma unroll
  for (int ni = 0; ni < 2; ++ni)
#pragma unroll
    for (int kk = 0; kk < 2; ++kk)
      bAddr[ni][kk] = 16384u + (unsigned)(wn4 + 8 * ni + u) * 256 +
                      ((unsigned)((c4 + 2 * kk + h) ^ u) << 4);

  // staging: per-lane pre-swizzled global source, lane-linear LDS dest.
  // Round covers 4KB = 16 pseudo-rows: Rq = t>>4, slot bs = t&15.
  const int bs_ = t & 15, Rq = t >> 4;
  const int b16 = bs_ ^ (Rq & 7);
  const int sc = b16 >> 2, slb = b16 & 3;
  const signed char* pA0 = Aq + (size_t)(m0 + 4 * Rq + sc) * K_DIM + slb * 16;
  const signed char* pA1 = pA0 + (size_t)64 * K_DIM;
  const signed char* pA2 = pA0 + (size_t)128 * K_DIM;
  const signed char* pA3 = pA0 + (size_t)192 * K_DIM;
  const signed char* pB0 = Bt + (size_t)(n0 + 4 * Rq + sc) * K_DIM + slb * 16;
  const signed char* pB1 = pB0 + (size_t)64 * K_DIM;

  int16v acc[4][2] = {};

#define STAGE(SO) do {                                    \
    gload16(pA0, lds + (SO) + t * 16);                    \
    gload16(pA1, lds + (SO) + 4096 + t * 16);             \
    gload16(pA2, lds + (SO) + 8192 + t * 16);             \
    gload16(pA3, lds + (SO) + 12288 + t * 16);            \
    gload16(pB0, lds + (SO) + 16384 + t * 16);            \
    gload16(pB1, lds + (SO) + 20480 + t * 16);            \
    pA0 += 64; pA1 += 64; pA2 += 64; pA3 += 64;           \
    pB0 += 64; pB1 += 64; } while (0)

#define MM_(A, B, CC) CC = __builtin_amdgcn_mfma_i32_32x32x32_i8(A, B, CC, 0, 0, 0)

  // COMP: 12 ds_read_b128 (kk=0 frags first), optional STAGE between reads and
  // MFMAs, then 2 setprio-wrapped 8-MFMA clusters. Compiler inserts fine lgkmcnt.
#define COMP(SO, STAGING) do {                                        \
    const signed char* sb = lds + (SO);                               \
    int4v b00 = *(const int4v*)(sb + bAddr[0][0]);                    \
    int4v b10 = *(const int4v*)(sb + bAddr[1][0]);                    \
    int4v a00 = *(const int4v*)(sb + aAddr[0][0]);                    \
    int4v a10 = *(const int4v*)(sb + aAddr[1][0]);                    \
    int4v a20 = *(const int4v*)(sb + aAddr[2][0]);                    \
    int4v a30 = *(const int4v*)(sb + aAddr[3][0]);                    \
    int4v b01 = *(const int4v*)(sb + bAddr[0][1]);                    \
    int4v b11 = *(const int4v*)(sb + bAddr[1][1]);                    \
    int4v a01 = *(const int4v*)(sb + aAddr[0][1]);                    \
    int4v a11 = *(const int4v*)(sb + aAddr[1][1]);                    \
    int4v a21 = *(const int4v*)(sb + aAddr[2][1]);                    \
    int4v a31 = *(const int4v*)(sb + aAddr[3][1]);                    \
    STAGING;                                                          \
    __builtin_amdgcn_s_setprio(1);                                    \
    MM_(a00, b00, acc[0][0]); MM_(a00, b10, acc[0][1]);               \
    MM_(a10, b00, acc[1][0]); MM_(a10, b10, acc[1][1]);               \
    MM_(a20, b00, acc[2][0]); MM_(a20, b10, acc[2][1]);               \
    MM_(a30, b00, acc[3][0]); MM_(a30, b10, acc[3][1]);               \
    __builtin_amdgcn_s_setprio(0);                                    \
    __builtin_amdgcn_s_setprio(1);                                    \
    MM_(a01, b01, acc[0][0]); MM_(a01, b11, acc[0][1]);               \
    MM_(a11, b01, acc[1][0]); MM_(a11, b11, acc[1][1]);               \
    MM_(a21, b01, acc[2][0]); MM_(a21, b11, acc[2][1]);               \
    MM_(a31, b01, acc[3][0]); MM_(a31, b11, acc[3][1]);               \
    __builtin_amdgcn_s_setprio(0);                                    \
  } while (0)

#define WAITN(N) asm volatile("s_waitcnt vmcnt(" #N ")" ::: "memory")
#define BARR do { __builtin_amdgcn_s_barrier();                       \
                  __builtin_amdgcn_sched_barrier(0); } while (0)

  // ITER(t): wait tile-t's 6 loads (t+1's 6 stay in flight), join, then
  // reads(t) -> stage(t+2) -> MFMAs(t). One barrier per tile.
#define ITER(SC, SN) do { WAITN(6); BARR; COMP(SC, STAGE(SN)); } while (0)

  // prologue: stage tiles 0 and 1
  STAGE(0);
  STAGE(24576);

#pragma unroll 1
  for (int g = 0; g < 20; ++g) {       // t = 3g .. 3g+2  (0..59)
    ITER(0, 49152);
    ITER(24576, 0);
    ITER(49152, 24576);
  }
  ITER(0, 49152);                      // t = 60 (stages 62)
  ITER(24576, 0);                      // t = 61 (stages 63)
  WAITN(6); BARR; COMP(49152, );       // t = 62 (63's loads still in flight)
  WAITN(0); BARR; COMP(0, );           // t = 63

#undef STAGE
#undef MM_
#undef COMP
#undef WAITN
#undef BARR
#undef ITER

  // epilogue: integer zero-point corrections (exact), then scale.
  // C/D layout (32x32): col = lane&31, row = (reg&3) + 8*(reg>>2) + 4*(lane>>5)
  const float amin = dec_f(mm[0]), amax = dec_f(mm[1]);
  const float bmin = dec_f(mm[2]), bmax = dec_f(mm[3]);
  const float sa = fmaxf((amax - amin) / 255.0f, 1e-8f);
  const float sb = fmaxf((bmax - bmin) / 255.0f, 1e-8f);
  const int za = (int)rintf(-amin / sa) - 128;
  const int zb = (int)rintf(-bmin / sb) - 128;
  const float sab = sa * sb;
  const int kzz = K_DIM * za * zb;
  const int wm = wm4 * 4, wn = wn4 * 4;
  const int col0 = n0 + wn + r32;
  const int cs0 = za * colsum[col0];
  const int cs1 = za * colsum[col0 + 32];
#pragma unroll
  for (int mi = 0; mi < 4; ++mi) {
    const int rbase = m0 + wm + mi * 32 + 4 * h;
#pragma unroll
    for (int r = 0; r < 16; ++r) {
      const int row = rbase + (r & 3) + 8 * (r >> 2);
      const int base = kzz - zb * rowsum[row];
      C[(size_t)row * N_COLS + col0]      = sab * (float)(acc[mi][0][r] + base - cs0);
      C[(size_t)row * N_COLS + col0 + 32] = sab * (float)(acc[mi][1][r] + base - cs1);
    }
  }
}

extern "C" void kernel_launch(void* const* d_in, const int* in_sizes, int n_in,
                              void* d_out, int out_size, void* d_ws, size_t ws_size,
                              hipStream_t stream) {
  const float* A = (const float*)d_in[0];
  const float* B = (const float*)d_in[1];
  float* C = (float*)d_out;
  char* ws = (char*)d_ws;
  signed char* Aq = (signed char*)(ws + OFF_AQ);
  signed char* Bt = (signed char*)(ws + OFF_BT);
  int* rowsum = (int*)(ws + OFF_RS);
  int* colsum = (int*)(ws + OFF_CS);
  unsigned* mm = (unsigned*)(ws + OFF_MM);

  init_k<<<17, 256, 0, stream>>>(mm, colsum);
  minmax_k<<<5120, 256, 0, stream>>>((const float4*)A, (const float4*)B, mm);
  quantA_k<<<M_ROWS, 256, 0, stream>>>(A, Aq, rowsum, mm);
  quantB_k<<<dim3(64, 64), 256, 0, stream>>>(B, Bt, colsum, mm);
  gemm_k<<<2048, 256, 0, stream>>>(Aq, Bt, C, rowsum, colsum, mm);
}

// Round 5
// 851.912 us; speedup vs baseline: 1.0500x; 1.0152x over previous
//
#include <hip/hip_runtime.h>

// QuantMatMul: fake-quant(A) @ fake-quant(B), computed exactly via i8 MFMA.
// A: [4,4096,4096] fp32 -> folded to M=16384 rows. B: [4096,4096] fp32 (K x N).
// C = s_a*s_b * ( A'B' - zb*rowsumA[m] - za*colsumB[n] + K*za*zb ),  A',B' in i8.
//
// Round 7: m201 8-phase template ported to i8 (T2+T3+T4+T5 combo).
// 256x256 tile, 512 thr / 8 waves (2Mx4N), wave 128x64 (acc[4][2]).
// K staged in 64-byte HALVES (64 total): 4 half-slots x 32KiB = 128KiB LDS.
// Per half, 2 phases: {6 ds_read_b128; 2 global_load_lds; s_barrier;
// setprio(1) 8xMFMA setprio(0); s_barrier}. ONE counted s_waitcnt vmcnt(8)
// per half (stage distance 3 halves; never 0 until epilogue peel).
// Per-lane pre-swizzled global source -> lane-linear LDS (0 conflicts, R4-R6).

#define K_DIM 4096
#define N_COLS 4096
#define M_ROWS 16384

typedef __attribute__((ext_vector_type(4))) int int4v;
typedef __attribute__((ext_vector_type(16))) int int16v;

// ---- workspace layout ----
static const size_t OFF_AQ = 0;                                  // 64 MiB  i8 [16384][4096] (plain)
static const size_t OFF_BT = (size_t)64 << 20;                   // 16 MiB  i8 [4096][4096] (B^T, plain)
static const size_t OFF_RS = OFF_BT + ((size_t)16 << 20);        // 64 KiB  int rowsumA
static const size_t OFF_CS = OFF_RS + (size_t)M_ROWS * 4;        // 16 KiB  int colsumB
static const size_t OFF_MM = OFF_CS + (size_t)N_COLS * 4;        // 64 B    minmax enc

// sortable encoding for float atomic min/max
__device__ __forceinline__ unsigned enc_f(float f) {
  unsigned u = __float_as_uint(f);
  return (u & 0x80000000u) ? ~u : (u | 0x80000000u);
}
__device__ __forceinline__ float dec_f(unsigned e) {
  unsigned u = (e & 0x80000000u) ? (e & 0x7fffffffu) : ~e;
  return __uint_as_float(u);
}

// reciprocal-multiply quantize: matches ref's clip(rint(x/s)+zp,0,255), -128 shift
__device__ __forceinline__ int quantize1(float x, float r, float zp) {
  return (int)(fminf(fmaxf(rintf(x * r) + zp, 0.0f), 255.0f)) - 128;
}

__device__ __forceinline__ void gload16(const void* g, void* l) {
  __builtin_amdgcn_global_load_lds(
      (const __attribute__((address_space(1))) unsigned int*)g,
      (__attribute__((address_space(3))) unsigned int*)l, 16, 0, 0);
}

// per-block inline param computation (deterministic; identical fp ops everywhere)
__device__ __forceinline__ void qparams_a(const unsigned* mm, float& ra, float& zpa) {
  const float amin = dec_f(mm[0]), amax = dec_f(mm[1]);
  const float sa = fmaxf((amax - amin) / 255.0f, 1e-8f);
  zpa = rintf(-amin / sa);
  ra = 1.0f / sa;
}
__device__ __forceinline__ void qparams_b(const unsigned* mm, float& rb, float& zpb) {
  const float bmin = dec_f(mm[2]), bmax = dec_f(mm[3]);
  const float sb = fmaxf((bmax - bmin) / 255.0f, 1e-8f);
  zpb = rintf(-bmin / sb);
  rb = 1.0f / sb;
}

// init: minmax sentinels + zero colsum (quantB accumulates into it atomically)
__global__ __launch_bounds__(256) void init_k(unsigned* __restrict__ mm,
                                              int* __restrict__ colsum) {
  const int i = blockIdx.x * 256 + threadIdx.x;
  if (i < N_COLS) colsum[i] = 0;
  if (i == N_COLS) {
    mm[0] = 0xFFFFFFFFu; mm[1] = 0u;   // A min/max (encoded)
    mm[2] = 0xFFFFFFFFu; mm[3] = 0u;   // B min/max
  }
}

// fused minmax over A (blocks 0..4095) and B (blocks 4096..5119)
__global__ __launch_bounds__(256) void minmax_k(const float4* __restrict__ A,
                                                const float4* __restrict__ B,
                                                unsigned* __restrict__ mm) {
  const bool isB = blockIdx.x >= 4096;
  const float4* __restrict__ x = isB ? B : A;
  const long n4 = isB ? (long)K_DIM * N_COLS / 4 : (long)M_ROWS * K_DIM / 4;
  const int nblk = isB ? 1024 : 4096;
  const int bid = isB ? (int)blockIdx.x - 4096 : (int)blockIdx.x;
  unsigned* m = mm + (isB ? 2 : 0);

  float lo = 3.402823466e38f, hi = -3.402823466e38f;
  long i = (long)bid * blockDim.x + threadIdx.x;
  const long stride = (long)nblk * blockDim.x;
  for (; i < n4; i += stride) {
    float4 v = x[i];
    lo = fminf(lo, fminf(fminf(v.x, v.y), fminf(v.z, v.w)));
    hi = fmaxf(hi, fmaxf(fmaxf(v.x, v.y), fmaxf(v.z, v.w)));
  }
  for (int off = 32; off; off >>= 1) {
    lo = fminf(lo, __shfl_down(lo, off));
    hi = fmaxf(hi, __shfl_down(hi, off));
  }
  __shared__ float slo[4], shi[4];
  const int t = threadIdx.x;
  if ((t & 63) == 0) { slo[t >> 6] = lo; shi[t >> 6] = hi; }
  __syncthreads();
  if (t == 0) {
    for (int w = 1; w < 4; w++) { lo = fminf(lo, slo[w]); hi = fmaxf(hi, shi[w]); }
    atomicMin(&m[0], enc_f(lo));
    atomicMax(&m[1], enc_f(hi));
  }
}

// one block per row: quantize (plain coalesced layout) + rowsum
__global__ __launch_bounds__(256) void quantA_k(const float* __restrict__ A,
                                                signed char* __restrict__ Aq,
                                                int* __restrict__ rowsum,
                                                const unsigned* __restrict__ mm) {
  float ra, zpa;
  qparams_a(mm, ra, zpa);
  const int row = blockIdx.x, t = threadIdx.x;
  const float4* src = (const float4*)(A + (size_t)row * K_DIM);
  unsigned* dst = (unsigned*)(Aq + (size_t)row * K_DIM);
  int sum = 0;
#pragma unroll
  for (int j = 0; j < 4; j++) {
    const int d = j * 256 + t;           // dword index in row (0..1023)
    float4 v = src[d];
    int q0 = quantize1(v.x, ra, zpa);
    int q1 = quantize1(v.y, ra, zpa);
    int q2 = quantize1(v.z, ra, zpa);
    int q3 = quantize1(v.w, ra, zpa);
    sum += q0 + q1 + q2 + q3;
    dst[d] = ((unsigned)q0 & 255u) | (((unsigned)q1 & 255u) << 8) |
             (((unsigned)q2 & 255u) << 16) | (((unsigned)q3 & 255u) << 24);
  }
  for (int off = 32; off; off >>= 1) sum += __shfl_down(sum, off);
  __shared__ int sw[4];
  if ((t & 63) == 0) sw[t >> 6] = sum;
  __syncthreads();
  if (t == 0) rowsum[row] = sw[0] + sw[1] + sw[2] + sw[3];
}

// quantize B, transpose to Bt[N][K] via 64x64 LDS tile; fused colsum via
// exact integer atomics (order-independent -> deterministic)
__global__ __launch_bounds__(256) void quantB_k(const float* __restrict__ B,
                                                signed char* __restrict__ Bt,
                                                int* __restrict__ colsum,
                                                const unsigned* __restrict__ mm) {
  float rb, zpb;
  qparams_b(mm, rb, zpb);
  __shared__ unsigned char s[64][72];
  const int n0 = blockIdx.x * 64, k0 = blockIdx.y * 64;
  const int t = threadIdx.x;
  const int kr = t >> 2, tl = t & 3;
  const float* rowp = B + (size_t)(k0 + kr) * N_COLS + n0;
#pragma unroll
  for (int j = 0; j < 4; j++) {
    const int fi = tl + j * 4;
    float4 v = *(const float4*)(rowp + fi * 4);
    int q0 = quantize1(v.x, rb, zpb);
    int q1 = quantize1(v.y, rb, zpb);
    int q2 = quantize1(v.z, rb, zpb);
    int q3 = quantize1(v.w, rb, zpb);
    *(unsigned*)&s[kr][fi * 4] = ((unsigned)q0 & 255u) | (((unsigned)q1 & 255u) << 8) |
                                 (((unsigned)q2 & 255u) << 16) | (((unsigned)q3 & 255u) << 24);
  }
  __syncthreads();
  const int nr = t >> 2;                 // output row within tile (n)
  const int kb = tl * 16;                // 16-byte K block within 64B chunk
  unsigned w[4];
  int psum = 0;
#pragma unroll
  for (int jj = 0; jj < 4; jj++) {
    unsigned b0 = s[kb + jj * 4 + 0][nr];
    unsigned b1 = s[kb + jj * 4 + 1][nr];
    unsigned b2 = s[kb + jj * 4 + 2][nr];
    unsigned b3 = s[kb + jj * 4 + 3][nr];
    w[jj] = b0 | (b1 << 8) | (b2 << 16) | (b3 << 24);
    psum += (int)(signed char)b0 + (int)(signed char)b1 +
            (int)(signed char)b2 + (int)(signed char)b3;
  }
  int4v o = {(int)w[0], (int)w[1], (int)w[2], (int)w[3]};
  *(int4v*)(Bt + (size_t)(n0 + nr) * K_DIM + (k0 + kb)) = o;
  psum += __shfl_xor(psum, 1);
  psum += __shfl_xor(psum, 2);
  if (tl == 0) atomicAdd(&colsum[n0 + nr], psum);
}

// ---- i8 GEMM: 256x256 tile, 8 waves (2M x 4N), wave = 128x64, K-halves ----
// Half-slot (32 KiB) = A 16KiB (64 pseudo-rows x 256B) + B 16KiB (64 p-rows).
// Pseudo-row R packs rows 4R..4R+3's 64B K-chunks; 16B block g at g ^ (R&7).
__global__ __launch_bounds__(512, 2) void gemm_k(const signed char* __restrict__ Aq,
                                                 const signed char* __restrict__ Bt,
                                                 float* __restrict__ C,
                                                 const int* __restrict__ rowsum,
                                                 const int* __restrict__ colsum,
                                                 const unsigned* __restrict__ mm) {
  __shared__ signed char lds[131072];   // 4 half-slots x 32 KiB
  const int t = threadIdx.x;

  // XCD-bijective swizzle: 1024 wgs, 8 XCDs, 128/XCD (8m x 16n chunk)
  const int orig = blockIdx.x;
  const int wgid = (orig & 7) * 128 + (orig >> 3);
  const int m0 = (wgid >> 4) * 256;
  const int n0 = (wgid & 15) * 256;

  const int w = t >> 6, l = t & 63;
  const int wm4 = (w >> 2) * 32;        // (wave m-offset)/4 : 2M waves of 128 rows
  const int wn4 = (w & 3) * 16;         // (wave n-offset)/4 : 4N waves of 64 cols
  const int r32 = l & 31, h = l >> 5;
  const int u = r32 >> 2, c4 = (r32 & 3) * 4;

  // tile-invariant LDS read addresses (half-slot-relative)
  unsigned aAddr[4][2], bAddr[2][2];
#pragma unroll
  for (int mi = 0; mi < 4; ++mi)
#pragma unroll
    for (int kk = 0; kk < 2; ++kk)
      aAddr[mi][kk] = (unsigned)(wm4 + 8 * mi + u) * 256 +
                      ((unsigned)((c4 + 2 * kk + h) ^ u) << 4);
#pragma unroll
  for (int ni = 0; ni < 2; ++ni)
#pragma unroll
    for (int kk = 0; kk < 2; ++kk)
      bAddr[ni][kk] = 16384u + (unsigned)(wn4 + 8 * ni + u) * 256 +
                      ((unsigned)((c4 + 2 * kk + h) ^ u) << 4);

  // staging: per-lane pre-swizzled global source, lane-linear LDS dest.
  // 8KB round = 32 pseudo-rows = 128 rows. Rq = t>>4, bs = t&15.
  const int bs_ = t & 15, Rq = t >> 4;
  const int b16 = bs_ ^ (Rq & 7);
  const int sc = b16 >> 2, slb = b16 & 3;
  const signed char* pA0 = Aq + (size_t)(m0 + 4 * Rq + sc) * K_DIM + slb * 16;
  const signed char* pA1 = pA0 + (size_t)128 * K_DIM;
  const signed char* pB0 = Bt + (size_t)(n0 + 4 * Rq + sc) * K_DIM + slb * 16;
  const signed char* pB1 = pB0 + (size_t)128 * K_DIM;

  int16v acc[4][2] = {};

#define STAGE_A(SN) do {                                  \
    gload16(pA0, lds + (SN) + t * 16);                    \
    gload16(pA1, lds + (SN) + 8192 + t * 16);             \
    pA0 += 64; pA1 += 64; } while (0)
#define STAGE_B(SN) do {                                  \
    gload16(pB0, lds + (SN) + 16384 + t * 16);            \
    gload16(pB1, lds + (SN) + 24576 + t * 16);            \
    pB0 += 64; pB1 += 64; } while (0)

#define MM_(A, B, CC) CC = __builtin_amdgcn_mfma_i32_32x32x32_i8(A, B, CC, 0, 0, 0)

#define RD6(SC, KK)                                                  \
    int4v b0 = *(const int4v*)(lds + (SC) + bAddr[0][KK]);           \
    int4v b1 = *(const int4v*)(lds + (SC) + bAddr[1][KK]);           \
    int4v a0 = *(const int4v*)(lds + (SC) + aAddr[0][KK]);           \
    int4v a1 = *(const int4v*)(lds + (SC) + aAddr[1][KK]);           \
    int4v a2 = *(const int4v*)(lds + (SC) + aAddr[2][KK]);           \
    int4v a3 = *(const int4v*)(lds + (SC) + aAddr[3][KK]);

#define MFMA8                                                        \
    __builtin_amdgcn_s_setprio(1);                                   \
    MM_(a0, b0, acc[0][0]); MM_(a0, b1, acc[0][1]);                  \
    MM_(a1, b0, acc[1][0]); MM_(a1, b1, acc[1][1]);                  \
    MM_(a2, b0, acc[2][0]); MM_(a2, b1, acc[2][1]);                  \
    MM_(a3, b0, acc[3][0]); MM_(a3, b1, acc[3][1]);                  \
    __builtin_amdgcn_s_setprio(0);

#define WAITN(N) asm volatile("s_waitcnt vmcnt(" #N ")" ::: "memory")
#define SBAR do { __builtin_amdgcn_sched_barrier(0);                 \
                  __builtin_amdgcn_s_barrier();                      \
                  __builtin_amdgcn_sched_barrier(0); } while (0)

  // Half H (2 phases): ph0 {reads kk0; stage A of H+3; bar; 8 MFMA; bar}
  //                    ph1 {reads kk1; stage B of H+3; bar; 8 MFMA; ENDW; bar}
  // ENDW = entry vmcnt-wait for half H+1 (counted; never 0 until the peel).
#define HALF(SC, SN, ENDW) do {                                      \
    { RD6(SC, 0) STAGE_A(SN); SBAR; MFMA8 } SBAR;                    \
    { RD6(SC, 1) STAGE_B(SN); SBAR; MFMA8 } ENDW; SBAR;              \
  } while (0)
#define HALF_NS(SC, ENDW) do {                                       \
    { RD6(SC, 0) SBAR; MFMA8 } SBAR;                                 \
    { RD6(SC, 1) SBAR; MFMA8 } ENDW; SBAR;                           \
  } while (0)

  // prologue: stage halves 0,1,2 (12 loads); entry wait for half 0
  STAGE_A(0);     STAGE_B(0);
  STAGE_A(32768); STAGE_B(32768);
  STAGE_A(65536); STAGE_B(65536);
  WAITN(8); SBAR;

#pragma unroll 1
  for (int g = 0; g < 15; ++g) {       // halves 0..59
    HALF(0,     98304, WAITN(8));
    HALF(32768, 0,     WAITN(8));
    HALF(65536, 32768, WAITN(8));
    HALF(98304, 65536, WAITN(8));
  }
  HALF(0, 98304, WAITN(8));            // H=60 (stages 63); 61,62,63 in flight
  HALF_NS(32768, WAITN(4));            // H=61
  HALF_NS(65536, WAITN(0));            // H=62
  HALF_NS(98304, );                    // H=63

#undef STAGE_A
#undef STAGE_B
#undef MM_
#undef RD6
#undef MFMA8
#undef WAITN
#undef SBAR
#undef HALF
#undef HALF_NS

  // epilogue: integer zero-point corrections (exact), then scale.
  // C/D layout (32x32): col = lane&31, row = (reg&3) + 8*(reg>>2) + 4*(lane>>5)
  const float amin = dec_f(mm[0]), amax = dec_f(mm[1]);
  const float bmin = dec_f(mm[2]), bmax = dec_f(mm[3]);
  const float sa = fmaxf((amax - amin) / 255.0f, 1e-8f);
  const float sb = fmaxf((bmax - bmin) / 255.0f, 1e-8f);
  const int za = (int)rintf(-amin / sa) - 128;
  const int zb = (int)rintf(-bmin / sb) - 128;
  const float sab = sa * sb;
  const int kzz = K_DIM * za * zb;
  const int wm = wm4 * 4, wn = wn4 * 4;
  const int col0 = n0 + wn + r32;
  const int cs0 = za * colsum[col0];
  const int cs1 = za * colsum[col0 + 32];
#pragma unroll
  for (int mi = 0; mi < 4; ++mi) {
    const int rbase = m0 + wm + mi * 32 + 4 * h;
#pragma unroll
    for (int r = 0; r < 16; ++r) {
      const int row = rbase + (r & 3) + 8 * (r >> 2);
      const int base = kzz - zb * rowsum[row];
      C[(size_t)row * N_COLS + col0]      = sab * (float)(acc[mi][0][r] + base - cs0);
      C[(size_t)row * N_COLS + col0 + 32] = sab * (float)(acc[mi][1][r] + base - cs1);
    }
  }
}

extern "C" void kernel_launch(void* const* d_in, const int* in_sizes, int n_in,
                              void* d_out, int out_size, void* d_ws, size_t ws_size,
                              hipStream_t stream) {
  const float* A = (const float*)d_in[0];
  const float* B = (const float*)d_in[1];
  float* C = (float*)d_out;
  char* ws = (char*)d_ws;
  signed char* Aq = (signed char*)(ws + OFF_AQ);
  signed char* Bt = (signed char*)(ws + OFF_BT);
  int* rowsum = (int*)(ws + OFF_RS);
  int* colsum = (int*)(ws + OFF_CS);
  unsigned* mm = (unsigned*)(ws + OFF_MM);

  init_k<<<17, 256, 0, stream>>>(mm, colsum);
  minmax_k<<<5120, 256, 0, stream>>>((const float4*)A, (const float4*)B, mm);
  quantA_k<<<M_ROWS, 256, 0, stream>>>(A, Aq, rowsum, mm);
  quantB_k<<<dim3(64, 64), 256, 0, stream>>>(B, Bt, colsum, mm);
  gemm_k<<<1024, 512, 0, stream>>>(Aq, Bt, C, rowsum, colsum, mm);
}

// Round 6
// 835.061 us; speedup vs baseline: 1.0712x; 1.0202x over previous
//
#include <hip/hip_runtime.h>

// QuantMatMul: fake-quant(A) @ fake-quant(B), computed exactly via i8 MFMA.
// A: [4,4096,4096] fp32 -> folded to M=16384 rows. B: [4096,4096] fp32 (K x N).
// C = s_a*s_b * ( A'B' - zb*rowsumA[m] - za*colsumB[n] + K*za*zb ),  A',B' in i8.
//
// Round 8: pre-pass overhaul (gemm_k is byte-identical to R7's 298us version).
//  - minmax_k: compile-time trip counts + 4 independent float4 loads in flight
//    (old loop had 1 outstanding load/wave -> latency-bound risk).
//  - prep2_k: quantA (+rowsum) and quantB (+transpose+colsum) fused into ONE
//    kernel (bid<2048: 8 A-rows each; else: 8 B-tiles each). 5->4 launches.
//  - gemm: R7 8-phase template (T2+T3+T4+T5), 256x256, counted vmcnt(8).

#define K_DIM 4096
#define N_COLS 4096
#define M_ROWS 16384

typedef __attribute__((ext_vector_type(4))) int int4v;
typedef __attribute__((ext_vector_type(16))) int int16v;

// ---- workspace layout ----
static const size_t OFF_AQ = 0;                                  // 64 MiB  i8 [16384][4096] (plain)
static const size_t OFF_BT = (size_t)64 << 20;                   // 16 MiB  i8 [4096][4096] (B^T, plain)
static const size_t OFF_RS = OFF_BT + ((size_t)16 << 20);        // 64 KiB  int rowsumA
static const size_t OFF_CS = OFF_RS + (size_t)M_ROWS * 4;        // 16 KiB  int colsumB
static const size_t OFF_MM = OFF_CS + (size_t)N_COLS * 4;        // 64 B    minmax enc

// sortable encoding for float atomic min/max
__device__ __forceinline__ unsigned enc_f(float f) {
  unsigned u = __float_as_uint(f);
  return (u & 0x80000000u) ? ~u : (u | 0x80000000u);
}
__device__ __forceinline__ float dec_f(unsigned e) {
  unsigned u = (e & 0x80000000u) ? (e & 0x7fffffffu) : ~e;
  return __uint_as_float(u);
}

// reciprocal-multiply quantize: matches ref's clip(rint(x/s)+zp,0,255), -128 shift
__device__ __forceinline__ int quantize1(float x, float r, float zp) {
  return (int)(fminf(fmaxf(rintf(x * r) + zp, 0.0f), 255.0f)) - 128;
}

__device__ __forceinline__ void gload16(const void* g, void* l) {
  __builtin_amdgcn_global_load_lds(
      (const __attribute__((address_space(1))) unsigned int*)g,
      (__attribute__((address_space(3))) unsigned int*)l, 16, 0, 0);
}

// per-block inline param computation (deterministic; identical fp ops everywhere)
__device__ __forceinline__ void qparams_a(const unsigned* mm, float& ra, float& zpa) {
  const float amin = dec_f(mm[0]), amax = dec_f(mm[1]);
  const float sa = fmaxf((amax - amin) / 255.0f, 1e-8f);
  zpa = rintf(-amin / sa);
  ra = 1.0f / sa;
}
__device__ __forceinline__ void qparams_b(const unsigned* mm, float& rb, float& zpb) {
  const float bmin = dec_f(mm[2]), bmax = dec_f(mm[3]);
  const float sb = fmaxf((bmax - bmin) / 255.0f, 1e-8f);
  zpb = rintf(-bmin / sb);
  rb = 1.0f / sb;
}

// init: minmax sentinels + zero colsum (prep2 accumulates into it atomically)
__global__ __launch_bounds__(256) void init_k(unsigned* __restrict__ mm,
                                              int* __restrict__ colsum) {
  const int i = blockIdx.x * 256 + threadIdx.x;
  if (i < N_COLS) colsum[i] = 0;
  if (i == N_COLS) {
    mm[0] = 0xFFFFFFFFu; mm[1] = 0u;   // A min/max (encoded)
    mm[2] = 0xFFFFFFFFu; mm[3] = 0u;   // B min/max
  }
}

// fused minmax over A (blocks 0..4095) and B (blocks 4096..5119).
// Compile-time trip counts; 4 independent loads in flight per thread.
__global__ __launch_bounds__(256) void minmax_k(const float4* __restrict__ A,
                                                const float4* __restrict__ B,
                                                unsigned* __restrict__ mm) {
  const bool isB = blockIdx.x >= 4096;
  const float4* __restrict__ x = isB ? B : A;
  const int bid = isB ? (int)blockIdx.x - 4096 : (int)blockIdx.x;
  unsigned* m = mm + (isB ? 2 : 0);
  const int t = threadIdx.x;
  const long i0 = (long)bid * 256 + t;
  const long STR = isB ? (long)1024 * 256 : (long)4096 * 256;

  float lo = 3.402823466e38f, hi = -3.402823466e38f;
#pragma unroll
  for (int g = 0; g < 4; ++g) {
    float4 v0 = x[i0 + (long)(4 * g + 0) * STR];
    float4 v1 = x[i0 + (long)(4 * g + 1) * STR];
    float4 v2 = x[i0 + (long)(4 * g + 2) * STR];
    float4 v3 = x[i0 + (long)(4 * g + 3) * STR];
    lo = fminf(lo, fminf(fminf(v0.x, v0.y), fminf(v0.z, v0.w)));
    hi = fmaxf(hi, fmaxf(fmaxf(v0.x, v0.y), fmaxf(v0.z, v0.w)));
    lo = fminf(lo, fminf(fminf(v1.x, v1.y), fminf(v1.z, v1.w)));
    hi = fmaxf(hi, fmaxf(fmaxf(v1.x, v1.y), fmaxf(v1.z, v1.w)));
    lo = fminf(lo, fminf(fminf(v2.x, v2.y), fminf(v2.z, v2.w)));
    hi = fmaxf(hi, fmaxf(fmaxf(v2.x, v2.y), fmaxf(v2.z, v2.w)));
    lo = fminf(lo, fminf(fminf(v3.x, v3.y), fminf(v3.z, v3.w)));
    hi = fmaxf(hi, fmaxf(fmaxf(v3.x, v3.y), fmaxf(v3.z, v3.w)));
  }
  for (int off = 32; off; off >>= 1) {
    lo = fminf(lo, __shfl_down(lo, off));
    hi = fmaxf(hi, __shfl_down(hi, off));
  }
  __shared__ float slo[4], shi[4];
  if ((t & 63) == 0) { slo[t >> 6] = lo; shi[t >> 6] = hi; }
  __syncthreads();
  if (t == 0) {
    for (int w = 1; w < 4; w++) { lo = fminf(lo, slo[w]); hi = fmaxf(hi, shi[w]); }
    atomicMin(&m[0], enc_f(lo));
    atomicMax(&m[1], enc_f(hi));
  }
}

// fused quant pass:
//   blocks 0..2047   : quantize 8 rows of A each (plain layout) + rowsum
//   blocks 2048..2559 : quantize+transpose 8 64x64 tiles of B each + colsum
__global__ __launch_bounds__(256) void prep2_k(const float* __restrict__ A,
                                               const float* __restrict__ B,
                                               signed char* __restrict__ Aq,
                                               signed char* __restrict__ Bt,
                                               int* __restrict__ rowsum,
                                               int* __restrict__ colsum,
                                               const unsigned* __restrict__ mm) {
  __shared__ unsigned char s[64][72];
  __shared__ int sw[4];
  const int t = threadIdx.x;
  const int bid = blockIdx.x;

  if (bid < 2048) {
    float ra, zpa;
    qparams_a(mm, ra, zpa);
#pragma unroll 1
    for (int rr = 0; rr < 8; ++rr) {
      const int row = bid * 8 + rr;
      const float4* src = (const float4*)(A + (size_t)row * K_DIM);
      unsigned* dst = (unsigned*)(Aq + (size_t)row * K_DIM);
      int sum = 0;
#pragma unroll
      for (int j = 0; j < 4; j++) {
        const int d = j * 256 + t;       // dword index in row (0..1023)
        float4 v = src[d];
        int q0 = quantize1(v.x, ra, zpa);
        int q1 = quantize1(v.y, ra, zpa);
        int q2 = quantize1(v.z, ra, zpa);
        int q3 = quantize1(v.w, ra, zpa);
        sum += q0 + q1 + q2 + q3;
        dst[d] = ((unsigned)q0 & 255u) | (((unsigned)q1 & 255u) << 8) |
                 (((unsigned)q2 & 255u) << 16) | (((unsigned)q3 & 255u) << 24);
      }
      for (int off = 32; off; off >>= 1) sum += __shfl_down(sum, off);
      if ((t & 63) == 0) sw[t >> 6] = sum;
      __syncthreads();
      if (t == 0) rowsum[row] = sw[0] + sw[1] + sw[2] + sw[3];
      __syncthreads();                   // protect sw reuse next row
    }
  } else {
    float rb, zpb;
    qparams_b(mm, rb, zpb);
    const int kr = t >> 2, tl = t & 3;
    const int nr = t >> 2, kb = tl * 16;
#pragma unroll 1
    for (int j8 = 0; j8 < 8; ++j8) {
      const int ti = (bid - 2048) * 8 + j8;     // 0..4095
      const int n0 = (ti & 63) * 64, k0 = (ti >> 6) * 64;
      const float* rowp = B + (size_t)(k0 + kr) * N_COLS + n0;
#pragma unroll
      for (int j = 0; j < 4; j++) {
        const int fi = tl + j * 4;
        float4 v = *(const float4*)(rowp + fi * 4);
        int q0 = quantize1(v.x, rb, zpb);
        int q1 = quantize1(v.y, rb, zpb);
        int q2 = quantize1(v.z, rb, zpb);
        int q3 = quantize1(v.w, rb, zpb);
        *(unsigned*)&s[kr][fi * 4] = ((unsigned)q0 & 255u) | (((unsigned)q1 & 255u) << 8) |
                                     (((unsigned)q2 & 255u) << 16) | (((unsigned)q3 & 255u) << 24);
      }
      __syncthreads();
      unsigned w[4];
      int psum = 0;
#pragma unroll
      for (int jj = 0; jj < 4; jj++) {
        unsigned b0 = s[kb + jj * 4 + 0][nr];
        unsigned b1 = s[kb + jj * 4 + 1][nr];
        unsigned b2 = s[kb + jj * 4 + 2][nr];
        unsigned b3 = s[kb + jj * 4 + 3][nr];
        w[jj] = b0 | (b1 << 8) | (b2 << 16) | (b3 << 24);
        psum += (int)(signed char)b0 + (int)(signed char)b1 +
                (int)(signed char)b2 + (int)(signed char)b3;
      }
      int4v o = {(int)w[0], (int)w[1], (int)w[2], (int)w[3]};
      *(int4v*)(Bt + (size_t)(n0 + nr) * K_DIM + (k0 + kb)) = o;
      psum += __shfl_xor(psum, 1);
      psum += __shfl_xor(psum, 2);
      if (tl == 0) atomicAdd(&colsum[n0 + nr], psum);
      __syncthreads();                   // protect s reuse next tile
    }
  }
}

// ---- i8 GEMM: 256x256 tile, 8 waves (2M x 4N), wave = 128x64, K-halves ----
// (byte-identical to R7: 42.5% MfmaUtil, 298us, 0 bank conflicts)
// Half-slot (32 KiB) = A 16KiB (64 pseudo-rows x 256B) + B 16KiB (64 p-rows).
// Pseudo-row R packs rows 4R..4R+3's 64B K-chunks; 16B block g at g ^ (R&7).
__global__ __launch_bounds__(512, 2) void gemm_k(const signed char* __restrict__ Aq,
                                                 const signed char* __restrict__ Bt,
                                                 float* __restrict__ C,
                                                 const int* __restrict__ rowsum,
                                                 const int* __restrict__ colsum,
                                                 const unsigned* __restrict__ mm) {
  __shared__ signed char lds[131072];   // 4 half-slots x 32 KiB
  const int t = threadIdx.x;

  // XCD-bijective swizzle: 1024 wgs, 8 XCDs, 128/XCD (8m x 16n chunk)
  const int orig = blockIdx.x;
  const int wgid = (orig & 7) * 128 + (orig >> 3);
  const int m0 = (wgid >> 4) * 256;
  const int n0 = (wgid & 15) * 256;

  const int w = t >> 6, l = t & 63;
  const int wm4 = (w >> 2) * 32;        // (wave m-offset)/4 : 2M waves of 128 rows
  const int wn4 = (w & 3) * 16;         // (wave n-offset)/4 : 4N waves of 64 cols
  const int r32 = l & 31, h = l >> 5;
  const int u = r32 >> 2, c4 = (r32 & 3) * 4;

  // tile-invariant LDS read addresses (half-slot-relative)
  unsigned aAddr[4][2], bAddr[2][2];
#pragma unroll
  for (int mi = 0; mi < 4; ++mi)
#pragma unroll
    for (int kk = 0; kk < 2; ++kk)
      aAddr[mi][kk] = (unsigned)(wm4 + 8 * mi + u) * 256 +
                      ((unsigned)((c4 + 2 * kk + h) ^ u) << 4);
#pragma unroll
  for (int ni = 0; ni < 2; ++ni)
#pragma unroll
    for (int kk = 0; kk < 2; ++kk)
      bAddr[ni][kk] = 16384u + (unsigned)(wn4 + 8 * ni + u) * 256 +
                      ((unsigned)((c4 + 2 * kk + h) ^ u) << 4);

  // staging: per-lane pre-swizzled global source, lane-linear LDS dest.
  // 8KB round = 32 pseudo-rows = 128 rows. Rq = t>>4, bs = t&15.
  const int bs_ = t & 15, Rq = t >> 4;
  const int b16 = bs_ ^ (Rq & 7);
  const int sc = b16 >> 2, slb = b16 & 3;
  const signed char* pA0 = Aq + (size_t)(m0 + 4 * Rq + sc) * K_DIM + slb * 16;
  const signed char* pA1 = pA0 + (size_t)128 * K_DIM;
  const signed char* pB0 = Bt + (size_t)(n0 + 4 * Rq + sc) * K_DIM + slb * 16;
  const signed char* pB1 = pB0 + (size_t)128 * K_DIM;

  int16v acc[4][2] = {};

#define STAGE_A(SN) do {                                  \
    gload16(pA0, lds + (SN) + t * 16);                    \
    gload16(pA1, lds + (SN) + 8192 + t * 16);             \
    pA0 += 64; pA1 += 64; } while (0)
#define STAGE_B(SN) do {                                  \
    gload16(pB0, lds + (SN) + 16384 + t * 16);            \
    gload16(pB1, lds + (SN) + 24576 + t * 16);            \
    pB0 += 64; pB1 += 64; } while (0)

#define MM_(A, B, CC) CC = __builtin_amdgcn_mfma_i32_32x32x32_i8(A, B, CC, 0, 0, 0)

#define RD6(SC, KK)                                                  \
    int4v b0 = *(const int4v*)(lds + (SC) + bAddr[0][KK]);           \
    int4v b1 = *(const int4v*)(lds + (SC) + bAddr[1][KK]);           \
    int4v a0 = *(const int4v*)(lds + (SC) + aAddr[0][KK]);           \
    int4v a1 = *(const int4v*)(lds + (SC) + aAddr[1][KK]);           \
    int4v a2 = *(const int4v*)(lds + (SC) + aAddr[2][KK]);           \
    int4v a3 = *(const int4v*)(lds + (SC) + aAddr[3][KK]);

#define MFMA8                                                        \
    __builtin_amdgcn_s_setprio(1);                                   \
    MM_(a0, b0, acc[0][0]); MM_(a0, b1, acc[0][1]);                  \
    MM_(a1, b0, acc[1][0]); MM_(a1, b1, acc[1][1]);                  \
    MM_(a2, b0, acc[2][0]); MM_(a2, b1, acc[2][1]);                  \
    MM_(a3, b0, acc[3][0]); MM_(a3, b1, acc[3][1]);                  \
    __builtin_amdgcn_s_setprio(0);

#define WAITN(N) asm volatile("s_waitcnt vmcnt(" #N ")" ::: "memory")
#define SBAR do { __builtin_amdgcn_sched_barrier(0);                 \
                  __builtin_amdgcn_s_barrier();                      \
                  __builtin_amdgcn_sched_barrier(0); } while (0)

  // Half H (2 phases): ph0 {reads kk0; stage A of H+3; bar; 8 MFMA; bar}
  //                    ph1 {reads kk1; stage B of H+3; bar; 8 MFMA; ENDW; bar}
  // ENDW = entry vmcnt-wait for half H+1 (counted; never 0 until the peel).
#define HALF(SC, SN, ENDW) do {                                      \
    { RD6(SC, 0) STAGE_A(SN); SBAR; MFMA8 } SBAR;                    \
    { RD6(SC, 1) STAGE_B(SN); SBAR; MFMA8 } ENDW; SBAR;              \
  } while (0)
#define HALF_NS(SC, ENDW) do {                                       \
    { RD6(SC, 0) SBAR; MFMA8 } SBAR;                                 \
    { RD6(SC, 1) SBAR; MFMA8 } ENDW; SBAR;                           \
  } while (0)

  // prologue: stage halves 0,1,2 (12 loads); entry wait for half 0
  STAGE_A(0);     STAGE_B(0);
  STAGE_A(32768); STAGE_B(32768);
  STAGE_A(65536); STAGE_B(65536);
  WAITN(8); SBAR;

#pragma unroll 1
  for (int g = 0; g < 15; ++g) {       // halves 0..59
    HALF(0,     98304, WAITN(8));
    HALF(32768, 0,     WAITN(8));
    HALF(65536, 32768, WAITN(8));
    HALF(98304, 65536, WAITN(8));
  }
  HALF(0, 98304, WAITN(8));            // H=60 (stages 63); 61,62,63 in flight
  HALF_NS(32768, WAITN(4));            // H=61
  HALF_NS(65536, WAITN(0));            // H=62
  HALF_NS(98304, );                    // H=63

#undef STAGE_A
#undef STAGE_B
#undef MM_
#undef RD6
#undef MFMA8
#undef WAITN
#undef SBAR
#undef HALF
#undef HALF_NS

  // epilogue: integer zero-point corrections (exact), then scale.
  // C/D layout (32x32): col = lane&31, row = (reg&3) + 8*(reg>>2) + 4*(lane>>5)
  const float amin = dec_f(mm[0]), amax = dec_f(mm[1]);
  const float bmin = dec_f(mm[2]), bmax = dec_f(mm[3]);
  const float sa = fmaxf((amax - amin) / 255.0f, 1e-8f);
  const float sb = fmaxf((bmax - bmin) / 255.0f, 1e-8f);
  const int za = (int)rintf(-amin / sa) - 128;
  const int zb = (int)rintf(-bmin / sb) - 128;
  const float sab = sa * sb;
  const int kzz = K_DIM * za * zb;
  const int wm = wm4 * 4, wn = wn4 * 4;
  const int col0 = n0 + wn + r32;
  const int cs0 = za * colsum[col0];
  const int cs1 = za * colsum[col0 + 32];
#pragma unroll
  for (int mi = 0; mi < 4; ++mi) {
    const int rbase = m0 + wm + mi * 32 + 4 * h;
#pragma unroll
    for (int r = 0; r < 16; ++r) {
      const int row = rbase + (r & 3) + 8 * (r >> 2);
      const int base = kzz - zb * rowsum[row];
      C[(size_t)row * N_COLS + col0]      = sab * (float)(acc[mi][0][r] + base - cs0);
      C[(size_t)row * N_COLS + col0 + 32] = sab * (float)(acc[mi][1][r] + base - cs1);
    }
  }
}

extern "C" void kernel_launch(void* const* d_in, const int* in_sizes, int n_in,
                              void* d_out, int out_size, void* d_ws, size_t ws_size,
                              hipStream_t stream) {
  const float* A = (const float*)d_in[0];
  const float* B = (const float*)d_in[1];
  float* C = (float*)d_out;
  char* ws = (char*)d_ws;
  signed char* Aq = (signed char*)(ws + OFF_AQ);
  signed char* Bt = (signed char*)(ws + OFF_BT);
  int* rowsum = (int*)(ws + OFF_RS);
  int* colsum = (int*)(ws + OFF_CS);
  unsigned* mm = (unsigned*)(ws + OFF_MM);

  init_k<<<17, 256, 0, stream>>>(mm, colsum);
  minmax_k<<<5120, 256, 0, stream>>>((const float4*)A, (const float4*)B, mm);
  prep2_k<<<2560, 256, 0, stream>>>(A, B, Aq, Bt, rowsum, colsum, mm);
  gemm_k<<<1024, 512, 0, stream>>>(Aq, Bt, C, rowsum, colsum, mm);
}